// Round 12
// baseline (120.711 us; speedup 1.0000x reference)
//
#include <hip/hip_runtime.h>
#include <hip/hip_bf16.h>
#include <math.h>
#include <cstddef>
#include <cstring>

// AttentionBlock: B=4, L=2048, C=512, H=8, Dk=64
// qkv = x @ W_in + b_in ; per head: causal-softmax(q k^T/8) @ v ; @ W_out + b_out + x

constexpr int B_SZ  = 4;
constexpr int L_SEQ = 2048;
constexpr int C_DIM = 512;
constexpr int H_N   = 8;
constexpr int DK    = 64;
constexpr int N_QKV = 1536;
constexpr int M_ROWS = B_SZ * L_SEQ; // 8192
// Q pre-scaled by Dk^-0.5 * log2(e) at producer => S in log2 domain.
constexpr float QSCALE = 0.125f * 1.44269504088896f;
constexpr float DEFER_THR = 11.5f;   // log2 units ~= e^8

typedef __attribute__((ext_vector_type(4))) float f32x4;
typedef __attribute__((ext_vector_type(16))) float f32x16;
typedef __attribute__((ext_vector_type(8))) short bf16x8;
typedef __attribute__((ext_vector_type(4))) unsigned int u32x4;

static __device__ inline ushort f2bf(float f) {
  unsigned u = __builtin_bit_cast(unsigned, f);
  u += 0x7fffu + ((u >> 16) & 1u);
  return (ushort)(u >> 16);
}

static __device__ inline unsigned pack_bf2(float a, float b) {
  const __hip_bfloat162 v = __float22bfloat162_rn(make_float2(a, b));
  unsigned u;
  __builtin_memcpy(&u, &v, 4);
  return u;
}

typedef __attribute__((address_space(1))) const unsigned int* gas1_t;
typedef __attribute__((address_space(3))) unsigned int* las3_t;
static __device__ inline void gload_lds16(const void* g, void* l) {
  __builtin_amdgcn_global_load_lds((gas1_t)g, (las3_t)l, 16, 0, 0);
}

// K tile [64 j][8 chunks of 8 d], phys chunk = (d/8) ^ (j&7).
// V tile [64 d][8 chunks of 8 j], phys chunk = (j/8) ^ (d&7).

// ----------------------------------------------------------- prep kernels
__global__ __launch_bounds__(256) void convert_bf16(
    const float* __restrict__ src, ushort* __restrict__ dst, int n4) {
  const int i = blockIdx.x * 256 + threadIdx.x;
  if (i < n4) {
    const float4 v = reinterpret_cast<const float4*>(src)[i];
    ushort4 o;
    o.x = f2bf(v.x); o.y = f2bf(v.y); o.z = f2bf(v.z); o.w = f2bf(v.w);
    reinterpret_cast<ushort4*>(dst)[i] = o;
  }
}

__global__ __launch_bounds__(256) void transpose_bf16(
    const float* __restrict__ src, ushort* __restrict__ dst, int R, int C) {
  __shared__ ushort T[64][65];
  const int c0 = blockIdx.x * 64, r0 = blockIdx.y * 64;
#pragma unroll
  for (int p = 0; p < 16; ++p) {
    const int idx = threadIdx.x + p * 256;
    const int r = idx >> 6, c = idx & 63;
    T[r][c] = f2bf(src[(size_t)(r0 + r) * C + c0 + c]);
  }
  __syncthreads();
#pragma unroll
  for (int p = 0; p < 16; ++p) {
    const int idx = threadIdx.x + p * 256;
    const int r = idx >> 6, c = idx & 63;
    dst[(size_t)(c0 + r) * R + r0 + c] = T[c][r];
  }
}

// -------------------------------------------------- bf16 MFMA GEMM 128x128
template <int EPI>
__global__ __launch_bounds__(256) void gemm_bf16(
    const ushort* __restrict__ A, const ushort* __restrict__ Bt,
    const float* __restrict__ bias, ushort* __restrict__ Qo,
    ushort* __restrict__ Ko, ushort* __restrict__ Vto,
    float* __restrict__ outF, const float* __restrict__ resid,
    int N, int K) {
  __shared__ ushort Al[128 * 32];
  __shared__ ushort Bl[128 * 32];
  const int tid = threadIdx.x;
  const int w = tid >> 6, l = tid & 63;
  const int cc = l & 15, gg = l >> 4;
  const int bm = blockIdx.y * 128, bn = blockIdx.x * 128;
  const int wr = w >> 1, wc = w & 1;
  f32x4 acc[4][4] = {};

  for (int k0 = 0; k0 < K; k0 += 32) {
#pragma unroll
    for (int q = 0; q < 2; ++q) {
      const int cbase = q * 256 + w * 64;
      const int c = cbase + l;
      gload_lds16(A + (size_t)(bm + (c >> 2)) * K + k0 + (c & 3) * 8,
                  &Al[cbase * 8]);
      gload_lds16(Bt + (size_t)(bn + (c >> 2)) * K + k0 + (c & 3) * 8,
                  &Bl[cbase * 8]);
    }
    __syncthreads();
    bf16x8 aF[4], bF[4];
#pragma unroll
    for (int i = 0; i < 4; ++i)
      aF[i] = *reinterpret_cast<const bf16x8*>(
          &Al[(wr * 64 + i * 16 + cc) * 32 + gg * 8]);
#pragma unroll
    for (int j = 0; j < 4; ++j)
      bF[j] = *reinterpret_cast<const bf16x8*>(
          &Bl[(wc * 64 + j * 16 + cc) * 32 + gg * 8]);
#pragma unroll
    for (int i = 0; i < 4; ++i)
#pragma unroll
      for (int j = 0; j < 4; ++j)
        acc[i][j] = __builtin_amdgcn_mfma_f32_16x16x32_bf16(aF[i], bF[j],
                                                            acc[i][j], 0, 0, 0);
    __syncthreads();
  }

  if (EPI == 0) {
#pragma unroll
    for (int j = 0; j < 4; ++j) {
      const int colbase = bn + wc * 64 + j * 16;
      const int h = colbase / 192, rem = colbase % 192;
      const int type = rem / 64, d = (rem % 64) + cc;
      const float bv = bias[colbase + cc];
#pragma unroll
      for (int i = 0; i < 4; ++i) {
        const int rowbase = bm + wr * 64 + i * 16 + 4 * gg;
        const int b = rowbase >> 11, ll = rowbase & 2047;
        const size_t bh32 = (size_t)(b * H_N + h) * 32;
        if (type == 0) {
#pragma unroll
          for (int r = 0; r < 4; ++r)
            Qo[((size_t)(b * H_N + h) * L_SEQ + ll + r) * DK + d] =
                f2bf((acc[i][j][r] + bv) * QSCALE);
        } else if (type == 1) {
#pragma unroll
          for (int r = 0; r < 4; ++r) {
            const int jg = ll + r;
            Ko[(bh32 + (jg >> 6)) * 4096 + (jg & 63) * 64 +
               (((d >> 3) ^ (jg & 7)) << 3) + (d & 7)] =
                f2bf(acc[i][j][r] + bv);
          }
        } else {
          ushort4 pk;
          pk.x = f2bf(acc[i][j][0] + bv);
          pk.y = f2bf(acc[i][j][1] + bv);
          pk.z = f2bf(acc[i][j][2] + bv);
          pk.w = f2bf(acc[i][j][3] + bv);
          const size_t idx = (bh32 + (ll >> 6)) * 4096 + (size_t)d * 64 +
                             ((((ll & 63) >> 3) ^ (d & 7)) << 3) + (ll & 7);
          *reinterpret_cast<ushort4*>(&Vto[idx]) = pk;
        }
      }
    }
  } else {
#pragma unroll
    for (int j = 0; j < 4; ++j) {
      const int col = bn + wc * 64 + j * 16 + cc;
      const float bv = bias[col];
#pragma unroll
      for (int i = 0; i < 4; ++i) {
        const int rowbase = bm + wr * 64 + i * 16 + 4 * gg;
#pragma unroll
        for (int r = 0; r < 4; ++r) {
          const size_t off = (size_t)(rowbase + r) * N + col;
          outF[off] = acc[i][j][r] + bv + resid[off];
        }
      }
    }
  }
}

// ------------------------------------- attention core: 32x32 swapped MFMA
// 512 blocks x 256 thr (4 waves x 32 q-rows = 128 q-rows/block).
// S^T = mfma(A=K, B=Q): lane owns q-col = lane&31 -> softmax lane-local.
// O^T = mfma(A=V^T, B=P^T): P B-frag built in registers (cvt_pk + one
// shfl_xor(32) pair-exchange per word pair) -> NO P LDS round-trip.
// K/V double-buffered LDS via global_load_lds (producer-swizzled tiles).
// qb order: heavy first, mirrored halves (CU pairs heavy+light). bh XCD-pin.
#define STAGE(buf, tile)                                                     \
  {                                                                          \
    const ushort* kg_ = KoB + (size_t)(tile) * 4096 + w * 1024 + lane * 8;   \
    const ushort* vg_ = VtB + (size_t)(tile) * 4096 + w * 1024 + lane * 8;   \
    gload_lds16(kg_, &Ks[buf][w * 1024]);                                    \
    gload_lds16(kg_ + 512, &Ks[buf][w * 1024 + 512]);                        \
    gload_lds16(vg_, &Vs[buf][w * 1024]);                                    \
    gload_lds16(vg_ + 512, &Vs[buf][w * 1024 + 512]);                        \
  }

__global__ __launch_bounds__(256) void attn_mfma32(
    const ushort* __restrict__ Q, const ushort* __restrict__ Ko,
    const ushort* __restrict__ Vt, ushort* __restrict__ attn_out) {
  __shared__ ushort Ks[2][4096];
  __shared__ ushort Vs[2][4096];
  const int id = blockIdx.x;
  const int bh = (id & 7) + 8 * ((id >> 3) & 3);
  const int hi5 = id >> 5;                        // 0..15
  const int qb = (hi5 < 8) ? (15 - hi5) : (hi5 - 8);  // heavy first
  const int tid = threadIdx.x;
  const int w = tid >> 6, lane = tid & 63;
  const int ql = lane & 31;                       // this lane's q-col
  const int hi = lane >> 5;
  const int b = bh >> 3, h = bh & 7;
  const ushort* KoB = Ko + (size_t)bh * 32 * 4096;
  const ushort* VtB = Vt + (size_t)bh * 32 * 4096;
  const int qg = qb * 128 + w * 32 + ql;          // global q row
  const int nt = 2 * qb + 2;                      // KV tiles for this block
  const int lastw = nt - 2 + (w >> 1);            // this wave's last tile

  // Q B-frags: lane holds Q[qg][d = 16s + 8hi + 0..7]
  bf16x8 qF[4];
  {
    const ushort* qp = Q + ((size_t)bh * L_SEQ + qg) * DK + 8 * hi;
#pragma unroll
    for (int s = 0; s < 4; ++s)
      qF[s] = *reinterpret_cast<const bf16x8*>(qp + 16 * s);
  }

  f32x16 O0 = {}, O1 = {};   // O^T: col q = ql, rows d = 32*dt + rmap
  float mrow = -INFINITY, lsum = 0.f;

  STAGE(0, 0);
  __syncthreads();

  for (int jt = 0; jt < nt; ++jt) {
    const int cur = jt & 1;
    if (jt + 1 < nt) STAGE(cur ^ 1, jt + 1);
    if (jt <= lastw) {
      const ushort* Kc = Ks[cur];
      const ushort* Vc = Vs[cur];
      // ---- QK^T: S0 (j 0..31), S1 (j 32..63); S[q][j], lane col = q
      f32x16 S0 = {}, S1 = {};
#pragma unroll
      for (int s = 0; s < 4; ++s) {
        const int cd = 2 * s + hi;
        const int ph = (cd ^ (ql & 7)) * 8;       // (32+ql)&7 == ql&7
        const bf16x8 k0 = *reinterpret_cast<const bf16x8*>(&Kc[ql * 64 + ph]);
        const bf16x8 k1 = *reinterpret_cast<const bf16x8*>(&Kc[(32 + ql) * 64 + ph]);
        S0 = __builtin_amdgcn_mfma_f32_32x32x16_bf16(k0, qF[s], S0, 0, 0, 0);
        S1 = __builtin_amdgcn_mfma_f32_32x32x16_bf16(k1, qF[s], S1, 0, 0, 0);
      }
      // ---- causal mask only on this wave's diagonal tile
      if (jt == lastw) {
        const int j0 = jt * 64;
#pragma unroll
        for (int r = 0; r < 16; ++r) {
          const int jm = j0 + (r & 3) + 8 * (r >> 2) + 4 * hi;
          if (jm > qg) S0[r] = -INFINITY;
          if (jm + 32 > qg) S1[r] = -INFINITY;
        }
      }
      // ---- defer-max (lane-local scalar state)
      float pm = S0[0];
#pragma unroll
      for (int r = 1; r < 16; ++r) pm = fmaxf(pm, S0[r]);
#pragma unroll
      for (int r = 0; r < 16; ++r) pm = fmaxf(pm, S1[r]);
      if (__any(pm > mrow + DEFER_THR)) {
        const float fm = fmaxf(pm, __shfl_xor(pm, 32, 64));
        const float mnew = fmaxf(mrow, fm);
        const float corr = __builtin_exp2f(mrow - mnew);  // 0 on first tile
        lsum *= corr;
#pragma unroll
        for (int r = 0; r < 16; ++r) { O0[r] *= corr; O1[r] *= corr; }
        mrow = mnew;
      }
      // ---- P = exp2(S - mrow)
#pragma unroll
      for (int r = 0; r < 16; ++r) {
        S0[r] = __builtin_exp2f(S0[r] - mrow); lsum += S0[r];
        S1[r] = __builtin_exp2f(S1[r] - mrow); lsum += S1[r];
      }
      // ---- pack P: step s covers j = 16s..16s+15.
      // own quads: uA[s] = j {16s+4hi, +1}, {+2,+3}; uB[s] = j {16s+8+4hi,..}
      // (regs: S_{s>>1}[8*(s&1) + 0..3] and [+4..7])
      unsigned uA0[4], uA1[4], uB0[4], uB1[4];
#pragma unroll
      for (int s = 0; s < 4; ++s) {
        const int base = 8 * (s & 1);
        if (s < 2) {
          uA0[s] = pack_bf2(S0[base + 0], S0[base + 1]);
          uA1[s] = pack_bf2(S0[base + 2], S0[base + 3]);
          uB0[s] = pack_bf2(S0[base + 4], S0[base + 5]);
          uB1[s] = pack_bf2(S0[base + 6], S0[base + 7]);
        } else {
          uA0[s] = pack_bf2(S1[base + 0], S1[base + 1]);
          uA1[s] = pack_bf2(S1[base + 2], S1[base + 3]);
          uB0[s] = pack_bf2(S1[base + 4], S1[base + 5]);
          uB1[s] = pack_bf2(S1[base + 6], S1[base + 7]);
        }
      }
      // ---- PV: O^T += V^T_frag x P^T_frag, in-register P exchange
#pragma unroll
      for (int s = 0; s < 4; ++s) {
        // exchange: hi=0 sends uB (j 16s+8..), receives partner uA (16s+4..)
        const unsigned t0 = hi ? uA0[s] : uB0[s];
        const unsigned t1 = hi ? uA1[s] : uB1[s];
        const unsigned x0 = (unsigned)__shfl_xor((int)t0, 32, 64);
        const unsigned x1 = (unsigned)__shfl_xor((int)t1, 32, 64);
        u32x4 pw;
        pw[0] = hi ? x0 : uA0[s];   // j 16s+0..1   (hi=1: 16s+8..9)
        pw[1] = hi ? x1 : uA1[s];   // j 16s+2..3   (hi=1: 16s+10..11)
        pw[2] = hi ? uB0[s] : x0;   // j 16s+4..5   (hi=1: 16s+12..13)
        pw[3] = hi ? uB1[s] : x1;   // j 16s+6..7   (hi=1: 16s+14..15)
        const bf16x8 pf = __builtin_bit_cast(bf16x8, pw);
        const int cj = 2 * s + hi;
        const int ph = (cj ^ (ql & 7)) * 8;
        const bf16x8 v0 = *reinterpret_cast<const bf16x8*>(&Vc[ql * 64 + ph]);
        const bf16x8 v1 = *reinterpret_cast<const bf16x8*>(&Vc[(32 + ql) * 64 + ph]);
        O0 = __builtin_amdgcn_mfma_f32_32x32x16_bf16(v0, pf, O0, 0, 0, 0);
        O1 = __builtin_amdgcn_mfma_f32_32x32x16_bf16(v1, pf, O1, 0, 0, 0);
      }
    }
    __syncthreads();  // drains prefetch DMA; all waves done with buf cur
  }

  // ---- combine partner lsum, normalize, store (lane owns row qg)
  const float ls = lsum + __shfl_xor(lsum, 32, 64);
  const float inv = 1.f / ls;
  ushort* orow = attn_out + ((size_t)b * L_SEQ + qg) * C_DIM + h * DK;
#pragma unroll
  for (int dt = 0; dt < 2; ++dt)
#pragma unroll
    for (int m = 0; m < 4; ++m) {
      ushort4 pk4;
      if (dt == 0) {
        pk4.x = f2bf(O0[4 * m + 0] * inv);
        pk4.y = f2bf(O0[4 * m + 1] * inv);
        pk4.z = f2bf(O0[4 * m + 2] * inv);
        pk4.w = f2bf(O0[4 * m + 3] * inv);
      } else {
        pk4.x = f2bf(O1[4 * m + 0] * inv);
        pk4.y = f2bf(O1[4 * m + 1] * inv);
        pk4.z = f2bf(O1[4 * m + 2] * inv);
        pk4.w = f2bf(O1[4 * m + 3] * inv);
      }
      *reinterpret_cast<ushort4*>(orow + 32 * dt + 8 * m + 4 * hi) = pk4;
    }
}

// ------------------------------------------------------------------- launch
extern "C" void kernel_launch(void* const* d_in, const int* in_sizes, int n_in,
                              void* d_out, int out_size, void* d_ws,
                              size_t ws_size, hipStream_t stream) {
  const float* x     = (const float*)d_in[0];
  const float* W_in  = (const float*)d_in[1];
  const float* b_in  = (const float*)d_in[2];
  const float* W_out = (const float*)d_in[3];
  const float* b_out = (const float*)d_in[4];
  float* out = (float*)d_out;

  ushort* xbf   = (ushort*)d_ws;                       // 8192x512
  ushort* WinT  = xbf + (size_t)M_ROWS * C_DIM;        // 1536x512
  ushort* WoutT = WinT + (size_t)N_QKV * C_DIM;        // 512x512
  ushort* Qo    = WoutT + (size_t)C_DIM * C_DIM;       // [BH,L,64]
  ushort* Ko    = Qo + (size_t)M_ROWS * C_DIM;         // [BH,32 tiles,4096]
  ushort* Vto   = Ko + (size_t)M_ROWS * C_DIM;         // [BH,32 tiles,4096]
  ushort* attnb = Vto + (size_t)M_ROWS * C_DIM;        // [8192,512]

  convert_bf16<<<(M_ROWS * C_DIM / 4 + 255) / 256, 256, 0, stream>>>(
      x, xbf, M_ROWS * C_DIM / 4);
  transpose_bf16<<<dim3(N_QKV / 64, C_DIM / 64), 256, 0, stream>>>(
      W_in, WinT, C_DIM, N_QKV);
  transpose_bf16<<<dim3(C_DIM / 64, C_DIM / 64), 256, 0, stream>>>(
      W_out, WoutT, C_DIM, C_DIM);

  gemm_bf16<0><<<dim3(N_QKV / 128, M_ROWS / 128), 256, 0, stream>>>(
      xbf, WinT, b_in, Qo, Ko, Vto, nullptr, nullptr, N_QKV, C_DIM);
  attn_mfma32<<<dim3(512, 1, 1), 256, 0, stream>>>(Qo, Ko, Vto, attnb);
  gemm_bf16<1><<<dim3(C_DIM / 128, M_ROWS / 128), 256, 0, stream>>>(
      attnb, WoutT, b_out, nullptr, nullptr, nullptr, out, x, C_DIM, C_DIM);
}

// Round 13
// 118.167 us; speedup vs baseline: 1.0215x; 1.0215x over previous
//
#include <hip/hip_runtime.h>
#include <hip/hip_bf16.h>
#include <math.h>
#include <cstddef>
#include <cstring>

// AttentionBlock: B=4, L=2048, C=512, H=8, Dk=64
// qkv = x @ W_in + b_in ; per head: causal-softmax(q k^T/8) @ v ; @ W_out + b_out + x

constexpr int B_SZ  = 4;
constexpr int L_SEQ = 2048;
constexpr int C_DIM = 512;
constexpr int H_N   = 8;
constexpr int DK    = 64;
constexpr int N_QKV = 1536;
constexpr int M_ROWS = B_SZ * L_SEQ; // 8192
// Q pre-scaled by Dk^-0.5 * log2(e) at producer => S in log2 domain.
constexpr float QSCALE = 0.125f * 1.44269504088896f;
constexpr float DEFER_THR = 11.5f;   // log2 units ~= e^8

typedef __attribute__((ext_vector_type(4))) float f32x4;
typedef __attribute__((ext_vector_type(16))) float f32x16;
typedef __attribute__((ext_vector_type(8))) short bf16x8;
typedef __attribute__((ext_vector_type(4))) unsigned int u32x4;

static __device__ inline ushort f2bf(float f) {
  unsigned u = __builtin_bit_cast(unsigned, f);
  u += 0x7fffu + ((u >> 16) & 1u);
  return (ushort)(u >> 16);
}

static __device__ inline unsigned pack_bf2(float a, float b) {
  const __hip_bfloat162 v = __float22bfloat162_rn(make_float2(a, b));
  unsigned u;
  __builtin_memcpy(&u, &v, 4);
  return u;
}

typedef __attribute__((address_space(1))) const unsigned int* gas1_t;
typedef __attribute__((address_space(3))) unsigned int* las3_t;
static __device__ inline void gload_lds16(const void* g, void* l) {
  __builtin_amdgcn_global_load_lds((gas1_t)g, (las3_t)l, 16, 0, 0);
}

// K tile [64 j][8 chunks of 8 d], phys chunk = (d/8) ^ (j&7).
// V tile [64 d][8 chunks of 8 j], phys chunk = (j/8) ^ (d&7).

// ----------------------------------------------------------- prep kernels
__global__ __launch_bounds__(256) void convert_bf16(
    const float* __restrict__ src, ushort* __restrict__ dst, int n4) {
  const int i = blockIdx.x * 256 + threadIdx.x;
  if (i < n4) {
    const float4 v = reinterpret_cast<const float4*>(src)[i];
    ushort4 o;
    o.x = f2bf(v.x); o.y = f2bf(v.y); o.z = f2bf(v.z); o.w = f2bf(v.w);
    reinterpret_cast<ushort4*>(dst)[i] = o;
  }
}

__global__ __launch_bounds__(256) void transpose_bf16(
    const float* __restrict__ src, ushort* __restrict__ dst, int R, int C) {
  __shared__ ushort T[64][65];
  const int c0 = blockIdx.x * 64, r0 = blockIdx.y * 64;
#pragma unroll
  for (int p = 0; p < 16; ++p) {
    const int idx = threadIdx.x + p * 256;
    const int r = idx >> 6, c = idx & 63;
    T[r][c] = f2bf(src[(size_t)(r0 + r) * C + c0 + c]);
  }
  __syncthreads();
#pragma unroll
  for (int p = 0; p < 16; ++p) {
    const int idx = threadIdx.x + p * 256;
    const int r = idx >> 6, c = idx & 63;
    dst[(size_t)(c0 + r) * R + r0 + c] = T[c][r];
  }
}

// -------------------------------------------------- bf16 MFMA GEMM 128x128
template <int EPI>
__global__ __launch_bounds__(256) void gemm_bf16(
    const ushort* __restrict__ A, const ushort* __restrict__ Bt,
    const float* __restrict__ bias, ushort* __restrict__ Qo,
    ushort* __restrict__ Ko, ushort* __restrict__ Vto,
    float* __restrict__ outF, const float* __restrict__ resid,
    int N, int K) {
  __shared__ ushort Al[128 * 32];
  __shared__ ushort Bl[128 * 32];
  const int tid = threadIdx.x;
  const int w = tid >> 6, l = tid & 63;
  const int cc = l & 15, gg = l >> 4;
  const int bm = blockIdx.y * 128, bn = blockIdx.x * 128;
  const int wr = w >> 1, wc = w & 1;
  f32x4 acc[4][4] = {};

  for (int k0 = 0; k0 < K; k0 += 32) {
#pragma unroll
    for (int q = 0; q < 2; ++q) {
      const int cbase = q * 256 + w * 64;
      const int c = cbase + l;
      gload_lds16(A + (size_t)(bm + (c >> 2)) * K + k0 + (c & 3) * 8,
                  &Al[cbase * 8]);
      gload_lds16(Bt + (size_t)(bn + (c >> 2)) * K + k0 + (c & 3) * 8,
                  &Bl[cbase * 8]);
    }
    __syncthreads();
    bf16x8 aF[4], bF[4];
#pragma unroll
    for (int i = 0; i < 4; ++i)
      aF[i] = *reinterpret_cast<const bf16x8*>(
          &Al[(wr * 64 + i * 16 + cc) * 32 + gg * 8]);
#pragma unroll
    for (int j = 0; j < 4; ++j)
      bF[j] = *reinterpret_cast<const bf16x8*>(
          &Bl[(wc * 64 + j * 16 + cc) * 32 + gg * 8]);
#pragma unroll
    for (int i = 0; i < 4; ++i)
#pragma unroll
      for (int j = 0; j < 4; ++j)
        acc[i][j] = __builtin_amdgcn_mfma_f32_16x16x32_bf16(aF[i], bF[j],
                                                            acc[i][j], 0, 0, 0);
    __syncthreads();
  }

  if (EPI == 0) {
#pragma unroll
    for (int j = 0; j < 4; ++j) {
      const int colbase = bn + wc * 64 + j * 16;
      const int h = colbase / 192, rem = colbase % 192;
      const int type = rem / 64, d = (rem % 64) + cc;
      const float bv = bias[colbase + cc];
#pragma unroll
      for (int i = 0; i < 4; ++i) {
        const int rowbase = bm + wr * 64 + i * 16 + 4 * gg;
        const int b = rowbase >> 11, ll = rowbase & 2047;
        const size_t bh32 = (size_t)(b * H_N + h) * 32;
        if (type == 0) {
#pragma unroll
          for (int r = 0; r < 4; ++r)
            Qo[((size_t)(b * H_N + h) * L_SEQ + ll + r) * DK + d] =
                f2bf((acc[i][j][r] + bv) * QSCALE);
        } else if (type == 1) {
#pragma unroll
          for (int r = 0; r < 4; ++r) {
            const int jg = ll + r;
            Ko[(bh32 + (jg >> 6)) * 4096 + (jg & 63) * 64 +
               (((d >> 3) ^ (jg & 7)) << 3) + (d & 7)] =
                f2bf(acc[i][j][r] + bv);
          }
        } else {
          ushort4 pk;
          pk.x = f2bf(acc[i][j][0] + bv);
          pk.y = f2bf(acc[i][j][1] + bv);
          pk.z = f2bf(acc[i][j][2] + bv);
          pk.w = f2bf(acc[i][j][3] + bv);
          const size_t idx = (bh32 + (ll >> 6)) * 4096 + (size_t)d * 64 +
                             ((((ll & 63) >> 3) ^ (d & 7)) << 3) + (ll & 7);
          *reinterpret_cast<ushort4*>(&Vto[idx]) = pk;
        }
      }
    }
  } else {
#pragma unroll
    for (int j = 0; j < 4; ++j) {
      const int col = bn + wc * 64 + j * 16 + cc;
      const float bv = bias[col];
#pragma unroll
      for (int i = 0; i < 4; ++i) {
        const int rowbase = bm + wr * 64 + i * 16 + 4 * gg;
#pragma unroll
        for (int r = 0; r < 4; ++r) {
          const size_t off = (size_t)(rowbase + r) * N + col;
          outF[off] = acc[i][j][r] + bv + resid[off];
        }
      }
    }
  }
}

// ------------------------------------- attention core: 32x32 swapped MFMA
// 1024 blocks x 128 thr (2 waves x 32 q-rows = 64 q-rows/block), R7-style
// balanced grid: qt = 31-(id>>5) heavy-first, bh = XCD-pinned -> ~uniform
// per-CU iteration totals, 4 blocks/CU (32KB LDS each).
// S^T = mfma32(A=K, B=Q): lane owns q-col -> softmax lane-local (mrow kept
// identical across the hi-pair by construction). O^T = mfma32(A=V^T, B=P^T);
// the P B-frag is built in registers: cvt_pk pairs + v_permlane32_swap_b32
// (VALU, no DS traffic, no cndmask) -> zero P LDS round-trip.
#define STAGE(buf, tile)                                                     \
  {                                                                          \
    const ushort* kg_ = KoB + (size_t)(tile) * 4096 + w * 2048 + lane * 8;   \
    const ushort* vg_ = VtB + (size_t)(tile) * 4096 + w * 2048 + lane * 8;   \
    _Pragma("unroll")                                                        \
    for (int i_ = 0; i_ < 4; ++i_) {                                         \
      gload_lds16(kg_ + i_ * 512, &Ks[buf][w * 2048 + i_ * 512]);            \
      gload_lds16(vg_ + i_ * 512, &Vs[buf][w * 2048 + i_ * 512]);            \
    }                                                                        \
  }

__global__ __launch_bounds__(128, 2) void attn_mfma32(
    const ushort* __restrict__ Q, const ushort* __restrict__ Ko,
    const ushort* __restrict__ Vt, ushort* __restrict__ attn_out) {
  __shared__ ushort Ks[2][4096];
  __shared__ ushort Vs[2][4096];
  const int id = blockIdx.x;
  const int bh = (id & 7) + 8 * ((id >> 3) & 3);
  const int qt = 31 - (id >> 5);
  const int tid = threadIdx.x;
  const int w = tid >> 6, lane = tid & 63;
  const int ql = lane & 31;                       // this lane's q-col
  const int hi = lane >> 5;
  const int b = bh >> 3, h = bh & 7;
  const ushort* KoB = Ko + (size_t)bh * 32 * 4096;
  const ushort* VtB = Vt + (size_t)bh * 32 * 4096;
  const int qg = qt * 64 + w * 32 + ql;           // global q row
  const int nt = qt + 1;                          // KV tiles for this block

  // Q B-frags: lane holds Q[qg][d = 16s + 8hi + 0..7]
  bf16x8 qF[4];
  {
    const ushort* qp = Q + ((size_t)bh * L_SEQ + qg) * DK + 8 * hi;
#pragma unroll
    for (int s = 0; s < 4; ++s)
      qF[s] = *reinterpret_cast<const bf16x8*>(qp + 16 * s);
  }

  f32x16 O0 = {}, O1 = {};   // O^T: col q = ql, rows d = 32*dt + rmap
  float mrow = -INFINITY, lsum = 0.f;

  STAGE(0, 0);
  __syncthreads();

  for (int jt = 0; jt < nt; ++jt) {
    const int cur = jt & 1;
    if (jt + 1 < nt) STAGE(cur ^ 1, jt + 1);
    const ushort* Kc = Ks[cur];
    const ushort* Vc = Vs[cur];
    // ---- QK^T: S0 (j 0..31), S1 (j 32..63); S^T[j][q], lane col = q
    f32x16 S0 = {}, S1 = {};
#pragma unroll
    for (int s = 0; s < 4; ++s) {
      const int cd = 2 * s + hi;
      const int ph = (cd ^ (ql & 7)) * 8;         // (32+ql)&7 == ql&7
      const bf16x8 k0 = *reinterpret_cast<const bf16x8*>(&Kc[ql * 64 + ph]);
      const bf16x8 k1 = *reinterpret_cast<const bf16x8*>(&Kc[(32 + ql) * 64 + ph]);
      S0 = __builtin_amdgcn_mfma_f32_32x32x16_bf16(k0, qF[s], S0, 0, 0, 0);
      S1 = __builtin_amdgcn_mfma_f32_32x32x16_bf16(k1, qF[s], S1, 0, 0, 0);
    }
    // ---- causal mask only on the diagonal (last) tile
    if (jt == qt) {
      const int j0 = jt * 64;
#pragma unroll
      for (int r = 0; r < 16; ++r) {
        const int jm = j0 + (r & 3) + 8 * (r >> 2) + 4 * hi;
        if (jm > qg) S0[r] = -INFINITY;
        if (jm + 32 > qg) S1[r] = -INFINITY;
      }
    }
    // ---- defer-max (lane-local; mrow stays pair-synchronized)
    float pm = S0[0];
#pragma unroll
    for (int r = 1; r < 16; ++r) pm = fmaxf(pm, S0[r]);
#pragma unroll
    for (int r = 0; r < 16; ++r) pm = fmaxf(pm, S1[r]);
    if (__any(pm > mrow + DEFER_THR)) {
      const float fm = fmaxf(pm, __shfl_xor(pm, 32, 64));
      const float mnew = fmaxf(mrow, fm);
      const float corr = __builtin_exp2f(mrow - mnew);  // 0 on first tile
      lsum *= corr;
#pragma unroll
      for (int r = 0; r < 16; ++r) { O0[r] *= corr; O1[r] *= corr; }
      mrow = mnew;
    }
    // ---- P = exp2(S - mrow)
#pragma unroll
    for (int r = 0; r < 16; ++r) {
      S0[r] = __builtin_exp2f(S0[r] - mrow); lsum += S0[r];
      S1[r] = __builtin_exp2f(S1[r] - mrow); lsum += S1[r];
    }
    // ---- PV with in-register P^T fragment assembly.
    // step s: lane needs P[ql][j = 16s + 8hi + 0..7].
    // own quads: uA* = j {16s+4hi+0..3}; uB* = j {16s+8+4hi+0..3}.
    // v_permlane32_swap_b32 a,b: a'={a_lo,b_lo}, b'={a_hi,b_hi} =>
    //   a' = word for k+0..1 pos, b' = word for k+4..5 pos, all lanes.
#pragma unroll
    for (int s = 0; s < 4; ++s) {
      const int base = 8 * (s & 1);
      unsigned a0, a1, b0, b1;
      if (s < 2) {
        a0 = pack_bf2(S0[base + 0], S0[base + 1]);
        a1 = pack_bf2(S0[base + 2], S0[base + 3]);
        b0 = pack_bf2(S0[base + 4], S0[base + 5]);
        b1 = pack_bf2(S0[base + 6], S0[base + 7]);
      } else {
        a0 = pack_bf2(S1[base + 0], S1[base + 1]);
        a1 = pack_bf2(S1[base + 2], S1[base + 3]);
        b0 = pack_bf2(S1[base + 4], S1[base + 5]);
        b1 = pack_bf2(S1[base + 6], S1[base + 7]);
      }
      asm volatile("v_permlane32_swap_b32 %0, %1" : "+v"(a0), "+v"(b0));
      asm volatile("v_permlane32_swap_b32 %0, %1" : "+v"(a1), "+v"(b1));
      u32x4 pw;
      pw[0] = a0; pw[1] = a1; pw[2] = b0; pw[3] = b1;
      const bf16x8 pf = __builtin_bit_cast(bf16x8, pw);
      const int cj = 2 * s + hi;
      const int ph = (cj ^ (ql & 7)) * 8;
      const bf16x8 v0 = *reinterpret_cast<const bf16x8*>(&Vc[ql * 64 + ph]);
      const bf16x8 v1 = *reinterpret_cast<const bf16x8*>(&Vc[(32 + ql) * 64 + ph]);
      O0 = __builtin_amdgcn_mfma_f32_32x32x16_bf16(v0, pf, O0, 0, 0, 0);
      O1 = __builtin_amdgcn_mfma_f32_32x32x16_bf16(v1, pf, O1, 0, 0, 0);
    }
    __syncthreads();  // drains prefetch DMA; both waves done with buf cur
  }

  // ---- combine pair lsum, normalize, store (lane owns row qg)
  const float ls = lsum + __shfl_xor(lsum, 32, 64);
  const float inv = 1.f / ls;
  ushort* orow = attn_out + ((size_t)b * L_SEQ + qg) * C_DIM + h * DK;
#pragma unroll
  for (int dt = 0; dt < 2; ++dt)
#pragma unroll
    for (int m = 0; m < 4; ++m) {
      ushort4 pk4;
      if (dt == 0) {
        pk4.x = f2bf(O0[4 * m + 0] * inv);
        pk4.y = f2bf(O0[4 * m + 1] * inv);
        pk4.z = f2bf(O0[4 * m + 2] * inv);
        pk4.w = f2bf(O0[4 * m + 3] * inv);
      } else {
        pk4.x = f2bf(O1[4 * m + 0] * inv);
        pk4.y = f2bf(O1[4 * m + 1] * inv);
        pk4.z = f2bf(O1[4 * m + 2] * inv);
        pk4.w = f2bf(O1[4 * m + 3] * inv);
      }
      *reinterpret_cast<ushort4*>(orow + 32 * dt + 8 * m + 4 * hi) = pk4;
    }
}

// ------------------------------------------------------------------- launch
extern "C" void kernel_launch(void* const* d_in, const int* in_sizes, int n_in,
                              void* d_out, int out_size, void* d_ws,
                              size_t ws_size, hipStream_t stream) {
  const float* x     = (const float*)d_in[0];
  const float* W_in  = (const float*)d_in[1];
  const float* b_in  = (const float*)d_in[2];
  const float* W_out = (const float*)d_in[3];
  const float* b_out = (const float*)d_in[4];
  float* out = (float*)d_out;

  ushort* xbf   = (ushort*)d_ws;                       // 8192x512
  ushort* WinT  = xbf + (size_t)M_ROWS * C_DIM;        // 1536x512
  ushort* WoutT = WinT + (size_t)N_QKV * C_DIM;        // 512x512
  ushort* Qo    = WoutT + (size_t)C_DIM * C_DIM;       // [BH,L,64]
  ushort* Ko    = Qo + (size_t)M_ROWS * C_DIM;         // [BH,32 tiles,4096]
  ushort* Vto   = Ko + (size_t)M_ROWS * C_DIM;         // [BH,32 tiles,4096]
  ushort* attnb = Vto + (size_t)M_ROWS * C_DIM;        // [8192,512]

  convert_bf16<<<(M_ROWS * C_DIM / 4 + 255) / 256, 256, 0, stream>>>(
      x, xbf, M_ROWS * C_DIM / 4);
  transpose_bf16<<<dim3(N_QKV / 64, C_DIM / 64), 256, 0, stream>>>(
      W_in, WinT, C_DIM, N_QKV);
  transpose_bf16<<<dim3(C_DIM / 64, C_DIM / 64), 256, 0, stream>>>(
      W_out, WoutT, C_DIM, C_DIM);

  gemm_bf16<0><<<dim3(N_QKV / 128, M_ROWS / 128), 256, 0, stream>>>(
      xbf, WinT, b_in, Qo, Ko, Vto, nullptr, nullptr, N_QKV, C_DIM);
  attn_mfma32<<<dim3(1024, 1, 1), 128, 0, stream>>>(Qo, Ko, Vto, attnb);
  gemm_bf16<1><<<dim3(C_DIM / 128, M_ROWS / 128), 256, 0, stream>>>(
      attnb, WoutT, b_out, nullptr, nullptr, nullptr, out, x, C_DIM, C_DIM);
}

// Round 14
// 100.580 us; speedup vs baseline: 1.2001x; 1.1749x over previous
//
#include <hip/hip_runtime.h>
#include <math.h>
#include <cstddef>

// AttentionBlock: B=4, L=2048, C=512, H=8, Dk=64
// qkv = x @ W_in + b_in ; per head: causal-softmax(q k^T/8) @ v ; @ W_out + b_out + x

constexpr int B_SZ  = 4;
constexpr int L_SEQ = 2048;
constexpr int C_DIM = 512;
constexpr int H_N   = 8;
constexpr int DK    = 64;
constexpr int N_QKV = 1536;
constexpr int M_ROWS = B_SZ * L_SEQ; // 8192
constexpr float SCALE = 0.125f;
constexpr float DEFER_THR = 8.f;     // defer-max threshold (P <= e^8)

typedef __attribute__((ext_vector_type(4))) float f32x4;
typedef __attribute__((ext_vector_type(8))) short bf16x8;

static __device__ inline ushort f2bf(float f) {
  unsigned u = __builtin_bit_cast(unsigned, f);
  u += 0x7fffu + ((u >> 16) & 1u);
  return (ushort)(u >> 16);
}

typedef __attribute__((address_space(1))) const unsigned int* gas1_t;
typedef __attribute__((address_space(3))) unsigned int* las3_t;
static __device__ inline void gload_lds16(const void* g, void* l) {
  __builtin_amdgcn_global_load_lds((gas1_t)g, (las3_t)l, 16, 0, 0);
}

// K/V tile format (producer-swizzled so LDS-linear staging => conflict-
// balanced ds_read_b128): per (bh, 64-j tile) an 8KB tile of [64 rows][8
// chunks of 16B]; chunk stored at (logical_chunk ^ (row & 7)). K tiles:
// row = j, elem d. V tiles: row = d, elem j.

// ----------------------------------------------------------- prep kernels
__global__ __launch_bounds__(256) void convert_bf16(
    const float* __restrict__ src, ushort* __restrict__ dst, int n4) {
  const int i = blockIdx.x * 256 + threadIdx.x;
  if (i < n4) {
    const float4 v = reinterpret_cast<const float4*>(src)[i];
    ushort4 o;
    o.x = f2bf(v.x); o.y = f2bf(v.y); o.z = f2bf(v.z); o.w = f2bf(v.w);
    reinterpret_cast<ushort4*>(dst)[i] = o;
  }
}

__global__ __launch_bounds__(256) void transpose_bf16(
    const float* __restrict__ src, ushort* __restrict__ dst, int R, int C) {
  __shared__ ushort T[64][65];
  const int c0 = blockIdx.x * 64, r0 = blockIdx.y * 64;
#pragma unroll
  for (int p = 0; p < 16; ++p) {
    const int idx = threadIdx.x + p * 256;
    const int r = idx >> 6, c = idx & 63;
    T[r][c] = f2bf(src[(size_t)(r0 + r) * C + c0 + c]);
  }
  __syncthreads();
#pragma unroll
  for (int p = 0; p < 16; ++p) {
    const int idx = threadIdx.x + p * 256;
    const int r = idx >> 6, c = idx & 63;
    dst[(size_t)(c0 + r) * R + r0 + c] = T[c][r];
  }
}

// -------------------------------------------------- bf16 MFMA GEMM 128x128
template <int EPI>
__global__ __launch_bounds__(256) void gemm_bf16(
    const ushort* __restrict__ A, const ushort* __restrict__ Bt,
    const float* __restrict__ bias, ushort* __restrict__ Qo,
    ushort* __restrict__ Ko, ushort* __restrict__ Vto,
    float* __restrict__ outF, const float* __restrict__ resid,
    int N, int K) {
  __shared__ ushort Al[128 * 32];
  __shared__ ushort Bl[128 * 32];
  const int tid = threadIdx.x;
  const int w = tid >> 6, l = tid & 63;
  const int cc = l & 15, gg = l >> 4;
  const int bm = blockIdx.y * 128, bn = blockIdx.x * 128;
  const int wr = w >> 1, wc = w & 1;
  f32x4 acc[4][4] = {};

  for (int k0 = 0; k0 < K; k0 += 32) {
#pragma unroll
    for (int q = 0; q < 2; ++q) {
      const int cbase = q * 256 + w * 64;
      const int c = cbase + l;
      gload_lds16(A + (size_t)(bm + (c >> 2)) * K + k0 + (c & 3) * 8,
                  &Al[cbase * 8]);
      gload_lds16(Bt + (size_t)(bn + (c >> 2)) * K + k0 + (c & 3) * 8,
                  &Bl[cbase * 8]);
    }
    __syncthreads();
    bf16x8 aF[4], bF[4];
#pragma unroll
    for (int i = 0; i < 4; ++i)
      aF[i] = *reinterpret_cast<const bf16x8*>(
          &Al[(wr * 64 + i * 16 + cc) * 32 + gg * 8]);
#pragma unroll
    for (int j = 0; j < 4; ++j)
      bF[j] = *reinterpret_cast<const bf16x8*>(
          &Bl[(wc * 64 + j * 16 + cc) * 32 + gg * 8]);
#pragma unroll
    for (int i = 0; i < 4; ++i)
#pragma unroll
      for (int j = 0; j < 4; ++j)
        acc[i][j] = __builtin_amdgcn_mfma_f32_16x16x32_bf16(aF[i], bF[j],
                                                            acc[i][j], 0, 0, 0);
    __syncthreads();
  }

  if (EPI == 0) {
#pragma unroll
    for (int j = 0; j < 4; ++j) {
      const int colbase = bn + wc * 64 + j * 16;
      const int h = colbase / 192, rem = colbase % 192;
      const int type = rem / 64, d = (rem % 64) + cc;
      const float bv = bias[colbase + cc];
#pragma unroll
      for (int i = 0; i < 4; ++i) {
        const int rowbase = bm + wr * 64 + i * 16 + 4 * gg;
        const int b = rowbase >> 11, ll = rowbase & 2047;
        const size_t bh32 = (size_t)(b * H_N + h) * 32;
        if (type == 0) {
#pragma unroll
          for (int r = 0; r < 4; ++r)
            Qo[((size_t)(b * H_N + h) * L_SEQ + ll + r) * DK + d] =
                f2bf(acc[i][j][r] + bv);
        } else if (type == 1) {
#pragma unroll
          for (int r = 0; r < 4; ++r) {
            const int jg = ll + r;
            Ko[(bh32 + (jg >> 6)) * 4096 + (jg & 63) * 64 +
               (((d >> 3) ^ (jg & 7)) << 3) + (d & 7)] =
                f2bf(acc[i][j][r] + bv);
          }
        } else {
          ushort4 pk;
          pk.x = f2bf(acc[i][j][0] + bv);
          pk.y = f2bf(acc[i][j][1] + bv);
          pk.z = f2bf(acc[i][j][2] + bv);
          pk.w = f2bf(acc[i][j][3] + bv);
          const size_t idx = (bh32 + (ll >> 6)) * 4096 + (size_t)d * 64 +
                             ((((ll & 63) >> 3) ^ (d & 7)) << 3) + (ll & 7);
          *reinterpret_cast<ushort4*>(&Vto[idx]) = pk;
        }
      }
    }
  } else {
#pragma unroll
    for (int j = 0; j < 4; ++j) {
      const int col = bn + wc * 64 + j * 16 + cc;
      const float bv = bias[col];
#pragma unroll
      for (int i = 0; i < 4; ++i) {
        const int rowbase = bm + wr * 64 + i * 16 + 4 * gg;
#pragma unroll
        for (int r = 0; r < 4; ++r) {
          const size_t off = (size_t)(rowbase + r) * N + col;
          outF[off] = acc[i][j][r] + bv + resid[off];
        }
      }
    }
  }
}

// ---------------------------------------------- attention core (bf16 MFMA)
// 1024 blocks x 256 thr (4 waves sharing one 64-row q-tile).
// BALANCED id->(qt,bh) mapping: x=id&7 (XCD pin, 4 bh/XCD L2-resident),
// u=id>>3, c=u&31, r=u>>5; bh=x+8r, qt=(r<2)?31-c:c. Under round-robin
// placement each CU's 4 co-resident blocks have qt={31-c,31-c,c,c} ->
// per-CU work is a CONSTANT 66 tile-iters (was 45..80, 1.7x imbalance),
// and the heavy tail keeps 8 waves/CU (two heavies paired).
// Loop body identical to round-7 (best measured, 49us): K/V tiles
// double-buffered in LDS via global_load_lds DMA (producer-swizzled,
// conflict-balanced ds_read_b128), 1-ahead prefetch drained by the
// end-of-iter barrier; deferred softmax (lane-local test, rescale rare);
// single final sum reduction.
#define STAGE(buf, tile)                                                     \
  {                                                                          \
    const ushort* kg_ = KoB + (size_t)(tile) * 4096 + w * 1024 + lane * 8;   \
    const ushort* vg_ = VtB + (size_t)(tile) * 4096 + w * 1024 + lane * 8;   \
    gload_lds16(kg_, &Ks[buf][w * 1024]);                                    \
    gload_lds16(kg_ + 512, &Ks[buf][w * 1024 + 512]);                        \
    gload_lds16(vg_, &Vs[buf][w * 1024]);                                    \
    gload_lds16(vg_ + 512, &Vs[buf][w * 1024 + 512]);                        \
  }

__global__ __launch_bounds__(256, 4) void attn_mfma(
    const ushort* __restrict__ Q, const ushort* __restrict__ Ko,
    const ushort* __restrict__ Vt, ushort* __restrict__ attn_out) {
  __shared__ ushort Ks[2][4096];
  __shared__ ushort Vs[2][4096];
  __shared__ ushort Pw_s[4][1024];
  const int id = blockIdx.x;
  const int x = id & 7;                 // XCD
  const int u = id >> 3;
  const int cb = u & 31;
  const int rb = u >> 5;                // 0..3 -> batch
  const int bh = x + 8 * rb;
  const int qt = (rb < 2) ? (31 - cb) : cb;
  const int tid = threadIdx.x;
  const int w = tid >> 6, lane = tid & 63;
  const int c = lane & 15, g = lane >> 4;
  const int b = bh >> 3, h = bh & 7;
  const ushort* KoB = Ko + (size_t)bh * 32 * 4096;
  const ushort* VtB = Vt + (size_t)bh * 32 * 4096;
  const int q0 = qt * 64 + w * 16;
  ushort* Pw = Pw_s[w];
  const int pc0 = (g ^ (c & 7)) * 8;        // phys chunk offset, logical g
  const int pc1 = ((g + 4) ^ (c & 7)) * 8;  // logical g+4

  bf16x8 qA[2];
  {
    const ushort* qp = Q + ((size_t)bh * L_SEQ + q0 + c) * DK + g * 8;
    qA[0] = *reinterpret_cast<const bf16x8*>(qp);
    qA[1] = *reinterpret_cast<const bf16x8*>(qp + 32);
  }

  f32x4 O[4] = {};
  float mrow[4] = {-INFINITY, -INFINITY, -INFINITY, -INFINITY};
  float lsum[4] = {};
  const f32x4 zero4 = {0.f, 0.f, 0.f, 0.f};

  STAGE(0, 0);
  __syncthreads();

  for (int jt = 0; jt <= qt; ++jt) {
    const int cur = jt & 1;
    if (jt < qt) STAGE(cur ^ 1, jt + 1);
    const ushort* Kc = Ks[cur];
    const ushort* Vc = Vs[cur];
    const int j0 = jt * 64;
    // ---- QK^T from LDS
    f32x4 S[4];
#pragma unroll
    for (int n = 0; n < 4; ++n) {
      const bf16x8 k0 = *reinterpret_cast<const bf16x8*>(&Kc[(n * 16 + c) * 64 + pc0]);
      const bf16x8 k1 = *reinterpret_cast<const bf16x8*>(&Kc[(n * 16 + c) * 64 + pc1]);
      S[n] = __builtin_amdgcn_mfma_f32_16x16x32_bf16(qA[0], k0, zero4, 0, 0, 0);
      S[n] = __builtin_amdgcn_mfma_f32_16x16x32_bf16(qA[1], k1, S[n], 0, 0, 0);
    }
    // ---- scale + causal mask
    const bool diag = (jt == qt);
#pragma unroll
    for (int n = 0; n < 4; ++n)
#pragma unroll
      for (int r = 0; r < 4; ++r) {
        float v = S[n][r] * SCALE;
        if (diag && (j0 + n * 16 + c) > (q0 + 4 * g + r)) v = -INFINITY;
        S[n][r] = v;
      }
    // ---- defer-max test (lane-local, no shuffles in steady state)
    float pm[4];
    int exceed = 0;
#pragma unroll
    for (int r = 0; r < 4; ++r) {
      pm[r] = fmaxf(fmaxf(S[0][r], S[1][r]), fmaxf(S[2][r], S[3][r]));
      exceed |= (pm[r] > mrow[r] + DEFER_THR);
    }
    if (__any(exceed)) {
#pragma unroll
      for (int r = 0; r < 4; ++r) {
        float fm = pm[r];
        fm = fmaxf(fm, __shfl_xor(fm, 1, 16));
        fm = fmaxf(fm, __shfl_xor(fm, 2, 16));
        fm = fmaxf(fm, __shfl_xor(fm, 4, 16));
        fm = fmaxf(fm, __shfl_xor(fm, 8, 16));
        const float mnew = fmaxf(mrow[r], fm);
        const float corr = __expf(mrow[r] - mnew);  // 0 on first tile
        lsum[r] *= corr;
#pragma unroll
        for (int t = 0; t < 4; ++t) O[t][r] *= corr;
        mrow[r] = mnew;
      }
    }
    // ---- P = exp(S - mrow)  (bounded by e^8), accumulate lane partials
#pragma unroll
    for (int n = 0; n < 4; ++n)
#pragma unroll
      for (int r = 0; r < 4; ++r) {
        const float p = __expf(S[n][r] - mrow[r]);
        S[n][r] = p;
        lsum[r] += p;
      }
    // ---- P -> bf16 via per-wave LDS re-layout into PV A-frag
#pragma unroll
    for (int n = 0; n < 4; ++n)
#pragma unroll
      for (int r = 0; r < 4; ++r) {
        const int row = 4 * g + r;
        Pw[row * 64 + ((2 * n + (c >> 3)) ^ (row & 7)) * 8 + (c & 7)] =
            f2bf(S[n][r]);
      }
    const bf16x8 pA0 = *reinterpret_cast<const bf16x8*>(&Pw[c * 64 + pc0]);
    const bf16x8 pA1 = *reinterpret_cast<const bf16x8*>(&Pw[c * 64 + pc1]);
    // ---- PV from LDS
#pragma unroll
    for (int t = 0; t < 4; ++t) {
      const bf16x8 v0 = *reinterpret_cast<const bf16x8*>(&Vc[(t * 16 + c) * 64 + pc0]);
      const bf16x8 v1 = *reinterpret_cast<const bf16x8*>(&Vc[(t * 16 + c) * 64 + pc1]);
      O[t] = __builtin_amdgcn_mfma_f32_16x16x32_bf16(pA0, v0, O[t], 0, 0, 0);
      O[t] = __builtin_amdgcn_mfma_f32_16x16x32_bf16(pA1, v1, O[t], 0, 0, 0);
    }
    __syncthreads();  // drains prefetch DMA; all waves done with buf cur
  }
  // ---- single final row-sum reduction + normalize
  float inv[4];
#pragma unroll
  for (int r = 0; r < 4; ++r) {
    float s = lsum[r];
    s += __shfl_xor(s, 1, 16);
    s += __shfl_xor(s, 2, 16);
    s += __shfl_xor(s, 4, 16);
    s += __shfl_xor(s, 8, 16);
    inv[r] = 1.f / s;
  }
#pragma unroll
  for (int t = 0; t < 4; ++t)
#pragma unroll
    for (int r = 0; r < 4; ++r)
      attn_out[((size_t)b * L_SEQ + q0 + 4 * g + r) * C_DIM + h * DK + t * 16 + c] =
          f2bf(O[t][r] * inv[r]);
}

// ------------------------------------------------------------------- launch
extern "C" void kernel_launch(void* const* d_in, const int* in_sizes, int n_in,
                              void* d_out, int out_size, void* d_ws,
                              size_t ws_size, hipStream_t stream) {
  const float* x     = (const float*)d_in[0];
  const float* W_in  = (const float*)d_in[1];
  const float* b_in  = (const float*)d_in[2];
  const float* W_out = (const float*)d_in[3];
  const float* b_out = (const float*)d_in[4];
  float* out = (float*)d_out;

  ushort* xbf   = (ushort*)d_ws;                       // 8192x512
  ushort* WinT  = xbf + (size_t)M_ROWS * C_DIM;        // 1536x512
  ushort* WoutT = WinT + (size_t)N_QKV * C_DIM;        // 512x512
  ushort* Qo    = WoutT + (size_t)C_DIM * C_DIM;       // [BH,L,64]
  ushort* Ko    = Qo + (size_t)M_ROWS * C_DIM;         // [BH,32 tiles,4096]
  ushort* Vto   = Ko + (size_t)M_ROWS * C_DIM;         // [BH,32 tiles,4096]
  ushort* attnb = Vto + (size_t)M_ROWS * C_DIM;        // [8192,512]

  convert_bf16<<<(M_ROWS * C_DIM / 4 + 255) / 256, 256, 0, stream>>>(
      x, xbf, M_ROWS * C_DIM / 4);
  transpose_bf16<<<dim3(N_QKV / 64, C_DIM / 64), 256, 0, stream>>>(
      W_in, WinT, C_DIM, N_QKV);
  transpose_bf16<<<dim3(C_DIM / 64, C_DIM / 64), 256, 0, stream>>>(
      W_out, WoutT, C_DIM, C_DIM);

  gemm_bf16<0><<<dim3(N_QKV / 128, M_ROWS / 128), 256, 0, stream>>>(
      xbf, WinT, b_in, Qo, Ko, Vto, nullptr, nullptr, N_QKV, C_DIM);
  attn_mfma<<<dim3(1024, 1, 1), 256, 0, stream>>>(Qo, Ko, Vto, attnb);
  gemm_bf16<1><<<dim3(C_DIM / 128, M_ROWS / 128), 256, 0, stream>>>(
      attnb, WoutT, b_out, nullptr, nullptr, nullptr, out, x, C_DIM, C_DIM);
}

// Round 15
// 95.159 us; speedup vs baseline: 1.2685x; 1.0570x over previous
//
#include <hip/hip_runtime.h>
#include <math.h>
#include <cstddef>

// AttentionBlock: B=4, L=2048, C=512, H=8, Dk=64
// qkv = x @ W_in + b_in ; per head: causal-softmax(q k^T/8) @ v ; @ W_out + b_out + x

constexpr int B_SZ  = 4;
constexpr int L_SEQ = 2048;
constexpr int C_DIM = 512;
constexpr int H_N   = 8;
constexpr int DK    = 64;
constexpr int N_QKV = 1536;
constexpr int M_ROWS = B_SZ * L_SEQ; // 8192
constexpr float SCALE = 0.125f;
constexpr float DEFER_THR = 8.f;     // defer-max threshold (P <= e^8)

typedef __attribute__((ext_vector_type(4))) float f32x4;
typedef __attribute__((ext_vector_type(8))) short bf16x8;

static __device__ inline ushort f2bf(float f) {
  unsigned u = __builtin_bit_cast(unsigned, f);
  u += 0x7fffu + ((u >> 16) & 1u);
  return (ushort)(u >> 16);
}

typedef __attribute__((address_space(1))) const unsigned int* gas1_t;
typedef __attribute__((address_space(3))) unsigned int* las3_t;
static __device__ inline void gload_lds16(const void* g, void* l) {
  __builtin_amdgcn_global_load_lds((gas1_t)g, (las3_t)l, 16, 0, 0);
}

// K/V tile format (producer-swizzled so LDS-linear staging => conflict-
// balanced ds_read_b128): per (bh, 64-j tile) an 8KB tile of [64 rows][8
// chunks of 16B]; chunk stored at (logical_chunk ^ (row & 7)). K tiles:
// row = j, elem d. V tiles: row = d, elem j.

// ------------------------------------------------- fused prep (1 launch)
// blocks [0,4096): convert x -> bf16 (float4/thread)
// blocks [4096,4288): transpose W_in  [512x1536] -> WinT [1536x512] bf16
// blocks [4288,4352): transpose W_out [512x512]  -> WoutT [512x512] bf16
__global__ __launch_bounds__(256) void prep_fused(
    const float* __restrict__ x, const float* __restrict__ W_in,
    const float* __restrict__ W_out, ushort* __restrict__ xbf,
    ushort* __restrict__ WinT, ushort* __restrict__ WoutT) {
  const int id = blockIdx.x;
  if (id < 4096) {
    const int i = id * 256 + threadIdx.x;
    const float4 v = reinterpret_cast<const float4*>(x)[i];
    ushort4 o;
    o.x = f2bf(v.x); o.y = f2bf(v.y); o.z = f2bf(v.z); o.w = f2bf(v.w);
    reinterpret_cast<ushort4*>(xbf)[i] = o;
    return;
  }
  __shared__ ushort T[64][65];
  const float* src;
  ushort* dst;
  int R, C, c0, r0;
  if (id < 4096 + 192) {
    const int t = id - 4096;
    src = W_in; dst = WinT; R = C_DIM; C = N_QKV;
    c0 = (t % 24) * 64; r0 = (t / 24) * 64;
  } else {
    const int t = id - 4288;
    src = W_out; dst = WoutT; R = C_DIM; C = C_DIM;
    c0 = (t % 8) * 64; r0 = (t / 8) * 64;
  }
#pragma unroll
  for (int p = 0; p < 16; ++p) {
    const int idx = threadIdx.x + p * 256;
    const int r = idx >> 6, c = idx & 63;
    T[r][c] = f2bf(src[(size_t)(r0 + r) * C + c0 + c]);
  }
  __syncthreads();
#pragma unroll
  for (int p = 0; p < 16; ++p) {
    const int idx = threadIdx.x + p * 256;
    const int r = idx >> 6, c = idx & 63;
    dst[(size_t)(c0 + r) * R + r0 + c] = T[c][r];
  }
}

// -------------------------------------------------- bf16 MFMA GEMM 128x128
template <int EPI>
__global__ __launch_bounds__(256) void gemm_bf16(
    const ushort* __restrict__ A, const ushort* __restrict__ Bt,
    const float* __restrict__ bias, ushort* __restrict__ Qo,
    ushort* __restrict__ Ko, ushort* __restrict__ Vto,
    float* __restrict__ outF, const float* __restrict__ resid,
    int N, int K) {
  __shared__ ushort Al[128 * 32];
  __shared__ ushort Bl[128 * 32];
  const int tid = threadIdx.x;
  const int w = tid >> 6, l = tid & 63;
  const int cc = l & 15, gg = l >> 4;
  const int bm = blockIdx.y * 128, bn = blockIdx.x * 128;
  const int wr = w >> 1, wc = w & 1;
  f32x4 acc[4][4] = {};

  for (int k0 = 0; k0 < K; k0 += 32) {
#pragma unroll
    for (int q = 0; q < 2; ++q) {
      const int cbase = q * 256 + w * 64;
      const int c = cbase + l;
      gload_lds16(A + (size_t)(bm + (c >> 2)) * K + k0 + (c & 3) * 8,
                  &Al[cbase * 8]);
      gload_lds16(Bt + (size_t)(bn + (c >> 2)) * K + k0 + (c & 3) * 8,
                  &Bl[cbase * 8]);
    }
    __syncthreads();
    bf16x8 aF[4], bF[4];
#pragma unroll
    for (int i = 0; i < 4; ++i)
      aF[i] = *reinterpret_cast<const bf16x8*>(
          &Al[(wr * 64 + i * 16 + cc) * 32 + gg * 8]);
#pragma unroll
    for (int j = 0; j < 4; ++j)
      bF[j] = *reinterpret_cast<const bf16x8*>(
          &Bl[(wc * 64 + j * 16 + cc) * 32 + gg * 8]);
#pragma unroll
    for (int i = 0; i < 4; ++i)
#pragma unroll
      for (int j = 0; j < 4; ++j)
        acc[i][j] = __builtin_amdgcn_mfma_f32_16x16x32_bf16(aF[i], bF[j],
                                                            acc[i][j], 0, 0, 0);
    __syncthreads();
  }

  if (EPI == 0) {
#pragma unroll
    for (int j = 0; j < 4; ++j) {
      const int colbase = bn + wc * 64 + j * 16;
      const int h = colbase / 192, rem = colbase % 192;
      const int type = rem / 64, d = (rem % 64) + cc;
      const float bv = bias[colbase + cc];
#pragma unroll
      for (int i = 0; i < 4; ++i) {
        const int rowbase = bm + wr * 64 + i * 16 + 4 * gg;
        const int b = rowbase >> 11, ll = rowbase & 2047;
        const size_t bh32 = (size_t)(b * H_N + h) * 32;
        if (type == 0) {
#pragma unroll
          for (int r = 0; r < 4; ++r)
            Qo[((size_t)(b * H_N + h) * L_SEQ + ll + r) * DK + d] =
                f2bf(acc[i][j][r] + bv);
        } else if (type == 1) {
#pragma unroll
          for (int r = 0; r < 4; ++r) {
            const int jg = ll + r;
            Ko[(bh32 + (jg >> 6)) * 4096 + (jg & 63) * 64 +
               (((d >> 3) ^ (jg & 7)) << 3) + (d & 7)] =
                f2bf(acc[i][j][r] + bv);
          }
        } else {
          ushort4 pk;
          pk.x = f2bf(acc[i][j][0] + bv);
          pk.y = f2bf(acc[i][j][1] + bv);
          pk.z = f2bf(acc[i][j][2] + bv);
          pk.w = f2bf(acc[i][j][3] + bv);
          const size_t idx = (bh32 + (ll >> 6)) * 4096 + (size_t)d * 64 +
                             ((((ll & 63) >> 3) ^ (d & 7)) << 3) + (ll & 7);
          *reinterpret_cast<ushort4*>(&Vto[idx]) = pk;
        }
      }
    }
  } else {
#pragma unroll
    for (int j = 0; j < 4; ++j) {
      const int col = bn + wc * 64 + j * 16 + cc;
      const float bv = bias[col];
#pragma unroll
      for (int i = 0; i < 4; ++i) {
        const int rowbase = bm + wr * 64 + i * 16 + 4 * gg;
#pragma unroll
        for (int r = 0; r < 4; ++r) {
          const size_t off = (size_t)(rowbase + r) * N + col;
          outF[off] = acc[i][j][r] + bv + resid[off];
        }
      }
    }
  }
}

// ---------------------------------------------- attention core (bf16 MFMA)
// EXACT round-7 kernel (best measured: 48.9us). 1024 blocks x 256 thr
// (4 waves / one 64-row q-tile). id&7 pins 4 (b,h) per XCD (L2-resident);
// qt = 31-(id>>5) heavy-first. K/V tiles double-buffered in LDS via
// global_load_lds DMA (producer-swizzled, conflict-balanced ds_read_b128);
// prefetch of tile jt+1 issued before compute on jt, drained by the
// end-of-iter barrier. Deferred softmax (lane-local test, rescale rare);
// single final sum reduction.
#define STAGE(buf, tile)                                                     \
  {                                                                          \
    const ushort* kg_ = KoB + (size_t)(tile) * 4096 + w * 1024 + lane * 8;   \
    const ushort* vg_ = VtB + (size_t)(tile) * 4096 + w * 1024 + lane * 8;   \
    gload_lds16(kg_, &Ks[buf][w * 1024]);                                    \
    gload_lds16(kg_ + 512, &Ks[buf][w * 1024 + 512]);                        \
    gload_lds16(vg_, &Vs[buf][w * 1024]);                                    \
    gload_lds16(vg_ + 512, &Vs[buf][w * 1024 + 512]);                        \
  }

__global__ __launch_bounds__(256, 4) void attn_mfma(
    const ushort* __restrict__ Q, const ushort* __restrict__ Ko,
    const ushort* __restrict__ Vt, ushort* __restrict__ attn_out) {
  __shared__ ushort Ks[2][4096];
  __shared__ ushort Vs[2][4096];
  __shared__ ushort Pw_s[4][1024];
  const int id = blockIdx.x;
  const int bh = (id & 7) + 8 * ((id >> 3) & 3);
  const int qt = 31 - (id >> 5);
  const int tid = threadIdx.x;
  const int w = tid >> 6, lane = tid & 63;
  const int c = lane & 15, g = lane >> 4;
  const int b = bh >> 3, h = bh & 7;
  const ushort* KoB = Ko + (size_t)bh * 32 * 4096;
  const ushort* VtB = Vt + (size_t)bh * 32 * 4096;
  const int q0 = qt * 64 + w * 16;
  ushort* Pw = Pw_s[w];
  const int pc0 = (g ^ (c & 7)) * 8;        // phys chunk offset, logical g
  const int pc1 = ((g + 4) ^ (c & 7)) * 8;  // logical g+4

  bf16x8 qA[2];
  {
    const ushort* qp = Q + ((size_t)bh * L_SEQ + q0 + c) * DK + g * 8;
    qA[0] = *reinterpret_cast<const bf16x8*>(qp);
    qA[1] = *reinterpret_cast<const bf16x8*>(qp + 32);
  }

  f32x4 O[4] = {};
  float mrow[4] = {-INFINITY, -INFINITY, -INFINITY, -INFINITY};
  float lsum[4] = {};
  const f32x4 zero4 = {0.f, 0.f, 0.f, 0.f};

  STAGE(0, 0);
  __syncthreads();

  for (int jt = 0; jt <= qt; ++jt) {
    const int cur = jt & 1;
    if (jt < qt) STAGE(cur ^ 1, jt + 1);
    const ushort* Kc = Ks[cur];
    const ushort* Vc = Vs[cur];
    const int j0 = jt * 64;
    // ---- QK^T from LDS
    f32x4 S[4];
#pragma unroll
    for (int n = 0; n < 4; ++n) {
      const bf16x8 k0 = *reinterpret_cast<const bf16x8*>(&Kc[(n * 16 + c) * 64 + pc0]);
      const bf16x8 k1 = *reinterpret_cast<const bf16x8*>(&Kc[(n * 16 + c) * 64 + pc1]);
      S[n] = __builtin_amdgcn_mfma_f32_16x16x32_bf16(qA[0], k0, zero4, 0, 0, 0);
      S[n] = __builtin_amdgcn_mfma_f32_16x16x32_bf16(qA[1], k1, S[n], 0, 0, 0);
    }
    // ---- scale + causal mask
    const bool diag = (jt == qt);
#pragma unroll
    for (int n = 0; n < 4; ++n)
#pragma unroll
      for (int r = 0; r < 4; ++r) {
        float v = S[n][r] * SCALE;
        if (diag && (j0 + n * 16 + c) > (q0 + 4 * g + r)) v = -INFINITY;
        S[n][r] = v;
      }
    // ---- defer-max test (lane-local, no shuffles in steady state)
    float pm[4];
    int exceed = 0;
#pragma unroll
    for (int r = 0; r < 4; ++r) {
      pm[r] = fmaxf(fmaxf(S[0][r], S[1][r]), fmaxf(S[2][r], S[3][r]));
      exceed |= (pm[r] > mrow[r] + DEFER_THR);
    }
    if (__any(exceed)) {
#pragma unroll
      for (int r = 0; r < 4; ++r) {
        float fm = pm[r];
        fm = fmaxf(fm, __shfl_xor(fm, 1, 16));
        fm = fmaxf(fm, __shfl_xor(fm, 2, 16));
        fm = fmaxf(fm, __shfl_xor(fm, 4, 16));
        fm = fmaxf(fm, __shfl_xor(fm, 8, 16));
        const float mnew = fmaxf(mrow[r], fm);
        const float corr = __expf(mrow[r] - mnew);  // 0 on first tile
        lsum[r] *= corr;
#pragma unroll
        for (int t = 0; t < 4; ++t) O[t][r] *= corr;
        mrow[r] = mnew;
      }
    }
    // ---- P = exp(S - mrow)  (bounded by e^8), accumulate lane partials
#pragma unroll
    for (int n = 0; n < 4; ++n)
#pragma unroll
      for (int r = 0; r < 4; ++r) {
        const float p = __expf(S[n][r] - mrow[r]);
        S[n][r] = p;
        lsum[r] += p;
      }
    // ---- P -> bf16 via per-wave LDS re-layout into PV A-frag
#pragma unroll
    for (int n = 0; n < 4; ++n)
#pragma unroll
      for (int r = 0; r < 4; ++r) {
        const int row = 4 * g + r;
        Pw[row * 64 + ((2 * n + (c >> 3)) ^ (row & 7)) * 8 + (c & 7)] =
            f2bf(S[n][r]);
      }
    const bf16x8 pA0 = *reinterpret_cast<const bf16x8*>(&Pw[c * 64 + pc0]);
    const bf16x8 pA1 = *reinterpret_cast<const bf16x8*>(&Pw[c * 64 + pc1]);
    // ---- PV from LDS
#pragma unroll
    for (int t = 0; t < 4; ++t) {
      const bf16x8 v0 = *reinterpret_cast<const bf16x8*>(&Vc[(t * 16 + c) * 64 + pc0]);
      const bf16x8 v1 = *reinterpret_cast<const bf16x8*>(&Vc[(t * 16 + c) * 64 + pc1]);
      O[t] = __builtin_amdgcn_mfma_f32_16x16x32_bf16(pA0, v0, O[t], 0, 0, 0);
      O[t] = __builtin_amdgcn_mfma_f32_16x16x32_bf16(pA1, v1, O[t], 0, 0, 0);
    }
    __syncthreads();  // drains prefetch DMA; all waves done with buf cur
  }
  // ---- single final row-sum reduction + normalize
  float inv[4];
#pragma unroll
  for (int r = 0; r < 4; ++r) {
    float s = lsum[r];
    s += __shfl_xor(s, 1, 16);
    s += __shfl_xor(s, 2, 16);
    s += __shfl_xor(s, 4, 16);
    s += __shfl_xor(s, 8, 16);
    inv[r] = 1.f / s;
  }
#pragma unroll
  for (int t = 0; t < 4; ++t)
#pragma unroll
    for (int r = 0; r < 4; ++r)
      attn_out[((size_t)b * L_SEQ + q0 + 4 * g + r) * C_DIM + h * DK + t * 16 + c] =
          f2bf(O[t][r] * inv[r]);
}

// ------------------------------------------------------------------- launch
extern "C" void kernel_launch(void* const* d_in, const int* in_sizes, int n_in,
                              void* d_out, int out_size, void* d_ws,
                              size_t ws_size, hipStream_t stream) {
  const float* x     = (const float*)d_in[0];
  const float* W_in  = (const float*)d_in[1];
  const float* b_in  = (const float*)d_in[2];
  const float* W_out = (const float*)d_in[3];
  const float* b_out = (const float*)d_in[4];
  float* out = (float*)d_out;

  ushort* xbf   = (ushort*)d_ws;                       // 8192x512
  ushort* WinT  = xbf + (size_t)M_ROWS * C_DIM;        // 1536x512
  ushort* WoutT = WinT + (size_t)N_QKV * C_DIM;        // 512x512
  ushort* Qo    = WoutT + (size_t)C_DIM * C_DIM;       // [BH,L,64]
  ushort* Ko    = Qo + (size_t)M_ROWS * C_DIM;         // [BH,32 tiles,4096]
  ushort* Vto   = Ko + (size_t)M_ROWS * C_DIM;         // [BH,32 tiles,4096]
  ushort* attnb = Vto + (size_t)M_ROWS * C_DIM;        // [8192,512]

  prep_fused<<<dim3(4352, 1, 1), 256, 0, stream>>>(
      x, W_in, W_out, xbf, WinT, WoutT);
  gemm_bf16<0><<<dim3(N_QKV / 128, M_ROWS / 128), 256, 0, stream>>>(
      xbf, WinT, b_in, Qo, Ko, Vto, nullptr, nullptr, N_QKV, C_DIM);
  attn_mfma<<<dim3(1024, 1, 1), 256, 0, stream>>>(Qo, Ko, Vto, attnb);
  gemm_bf16<1><<<dim3(C_DIM / 128, M_ROWS / 128), 256, 0, stream>>>(
      attnb, WoutT, b_out, nullptr, nullptr, nullptr, out, x, C_DIM, C_DIM);
}